// Round 4
// baseline (5450.516 us; speedup 1.0000x reference)
//
#include <hip/hip_runtime.h>
#include <math.h>

#define N_NODES 100000
#define N_EDGES 1600000
#define IN_C 128
#define HID_C 128
#define OUT_C 64
#define NLAYERS 4
#define KSTEPS 10
#define ALPHA 0.1f
#define LN_EPS 1e-5f

#define SCAN_N (N_NODES + 1)
#define SCAN_BLOCKS ((SCAN_N + 1023) / 1024)     // 98
#define EP_CAP 2400000                            // 1.6M edges + <=7 pad/node

__device__ __forceinline__ float gelu_exact(float x) {
    return 0.5f * x * (1.0f + erff(x * 0.70710678118654752f));
}

// ---------------------------------------------------------------------------
// CSR build: count in-degree per dst
__global__ void count_k(const int* __restrict__ dst, int* __restrict__ counts) {
    int e = blockIdx.x * blockDim.x + threadIdx.x;
    if (e < N_EDGES) atomicAdd(&counts[dst[e]], 1);
}

// scan1: per-block sums of padded (x8) counts
__global__ __launch_bounds__(1024) void scan1_k(const int* __restrict__ counts,
                                                int* __restrict__ bsum) {
    __shared__ int s[1024];
    int i = blockIdx.x * 1024 + threadIdx.x;
    int c = 0;
    if (i < N_NODES) c = (counts[i] + 7) & ~7;
    s[threadIdx.x] = c;
    __syncthreads();
    for (int off = 512; off; off >>= 1) {
        if (threadIdx.x < off) s[threadIdx.x] += s[threadIdx.x + off];
        __syncthreads();
    }
    if (threadIdx.x == 0) bsum[blockIdx.x] = s[0];
}

// scan2: exclusive scan of the 98 block sums
__global__ void scan2_k(int* __restrict__ bsum) {
    __shared__ int s[128];
    int t = threadIdx.x;
    s[t] = (t < SCAN_BLOCKS) ? bsum[t] : 0;
    __syncthreads();
    for (int off = 1; off < 128; off <<= 1) {
        int v = (t >= off) ? s[t - off] : 0;
        __syncthreads();
        s[t] += v;
        __syncthreads();
    }
    if (t < SCAN_BLOCKS) bsum[t] = (t == 0) ? 0 : s[t - 1];
}

// scan3: per-block exclusive scan + block offset -> row_off / fill_pos
__global__ __launch_bounds__(1024) void scan3_k(const int* __restrict__ counts,
                                                const int* __restrict__ bsum,
                                                int* __restrict__ row_off,
                                                int* __restrict__ fill_pos) {
    __shared__ int s[1024];
    int i = blockIdx.x * 1024 + threadIdx.x;
    int c = 0;
    if (i < N_NODES) c = (counts[i] + 7) & ~7;
    s[threadIdx.x] = c;
    __syncthreads();
    for (int off = 1; off < 1024; off <<= 1) {
        int v = (threadIdx.x >= off) ? s[threadIdx.x - off] : 0;
        __syncthreads();
        s[threadIdx.x] += v;
        __syncthreads();
    }
    if (i <= N_NODES) {
        int excl = s[threadIdx.x] - c + bsum[blockIdx.x];
        row_off[i] = excl;
        fill_pos[i] = excl;
    }
}

// Bucket edges by dst; pack (src*32 [float4-row offset], (1-alpha)*w).
// Pad slots stay (0,0.0f) from the ep memset -> gather row 0 (L1-hot) * 0.
__global__ void bucket_k(const int* __restrict__ src, const int* __restrict__ dst,
                         const float* __restrict__ w,
                         int* __restrict__ fill_pos, int2* __restrict__ ep) {
    int e = blockIdx.x * blockDim.x + threadIdx.x;
    if (e >= N_EDGES) return;
    int d = dst[e];
    int pos = atomicAdd(&fill_pos[d], 1);
    float ws = (1.0f - ALPHA) * w[e];
    ep[pos] = make_int2(src[e] << 5, __float_as_int(ws));
}

// ---------------------------------------------------------------------------
// Encoder: H = gelu(LN(x @ Wenc^T)).
// block=1024 (16 waves); wave: 4 rows; lane holds channel pair (2l, 2l+1).
// x rows loaded as float4 (wave-uniform); weights via ds_read_b64, 2-way free.
__global__ __launch_bounds__(1024) void encoder_k(
        const float* __restrict__ x, const float* __restrict__ Wenc,
        const float* __restrict__ gamma, const float* __restrict__ beta,
        float* __restrict__ H) {
    __shared__ float WT[IN_C * 130];           // float-stride 130: WT[k*130+c]
    for (int i = threadIdx.x; i < IN_C * HID_C; i += 1024) {
        int c = i >> 7, k = i & 127;
        WT[k * 130 + c] = Wenc[i];             // bank (2k+c)%32: 2-way, free
    }
    __syncthreads();
    int lane = threadIdx.x & 63;
    int wid  = threadIdx.x >> 6;
    const float2* WT2 = (const float2*)WT;     // index k*65 + lane
    float2 gb = ((const float2*)gamma)[lane];
    float2 bb = ((const float2*)beta)[lane];
    const float4* X4 = (const float4*)x;
    int wstride = gridDim.x * 16;
    for (int grp = blockIdx.x * 16 + wid; grp * 4 < N_NODES; grp += wstride) {
        int r0 = grp * 4;
        float a0x = 0, a0y = 0, a1x = 0, a1y = 0;
        float a2x = 0, a2y = 0, a3x = 0, a3y = 0;
#pragma unroll 2
        for (int k4 = 0; k4 < 32; ++k4) {
            float4 xv0 = X4[(size_t)r0 * 32 + k4];
            float4 xv1 = X4[(size_t)(r0 + 1) * 32 + k4];
            float4 xv2 = X4[(size_t)(r0 + 2) * 32 + k4];
            float4 xv3 = X4[(size_t)(r0 + 3) * 32 + k4];
            int k = k4 * 4;
            float2 w0 = WT2[(k + 0) * 65 + lane];
            float2 w1 = WT2[(k + 1) * 65 + lane];
            float2 w2 = WT2[(k + 2) * 65 + lane];
            float2 w3 = WT2[(k + 3) * 65 + lane];
#define ENC_ROW(ax, ay, xv)                                      \
            ax = fmaf(xv.x, w0.x, ax); ay = fmaf(xv.x, w0.y, ay); \
            ax = fmaf(xv.y, w1.x, ax); ay = fmaf(xv.y, w1.y, ay); \
            ax = fmaf(xv.z, w2.x, ax); ay = fmaf(xv.z, w2.y, ay); \
            ax = fmaf(xv.w, w3.x, ax); ay = fmaf(xv.w, w3.y, ay);
            ENC_ROW(a0x, a0y, xv0)
            ENC_ROW(a1x, a1y, xv1)
            ENC_ROW(a2x, a2y, xv2)
            ENC_ROW(a3x, a3y, xv3)
#undef ENC_ROW
        }
        float2* H2 = (float2*)H;
#define ENC_EPI(ax, ay, row)                                               \
        {                                                                   \
            float sum = ax + ay;                                            \
            for (int off = 32; off; off >>= 1) sum += __shfl_xor(sum, off); \
            float mu = sum * (1.0f / 128.0f);                               \
            float d0 = ax - mu, d1 = ay - mu;                               \
            float vs = d0 * d0 + d1 * d1;                                   \
            for (int off = 32; off; off >>= 1) vs += __shfl_xor(vs, off);   \
            float inv = rsqrtf(vs * (1.0f / 128.0f) + LN_EPS);              \
            float2 o;                                                       \
            o.x = gelu_exact(gb.x * d0 * inv + bb.x);                       \
            o.y = gelu_exact(gb.y * d1 * inv + bb.y);                       \
            H2[(size_t)(row)*64 + lane] = o;                                \
        }
        ENC_EPI(a0x, a0y, r0)
        ENC_EPI(a1x, a1y, r0 + 1)
        ENC_EPI(a2x, a2y, r0 + 2)
        ENC_EPI(a3x, a3y, r0 + 3)
#undef ENC_EPI
    }
}

// ---------------------------------------------------------------------------
// One APPNP step (pull). 2 nodes per wave: half = lane>>5, l32 = lane&31,
// lane holds float4 = channels 4*l32..4*l32+3 of its node. Each gather
// instruction fetches 1 KB (two 512 B rows); 8 in flight. Edge params
// cooperatively loaded per half and half-broadcast via shfl. Degrees padded
// to x8; pad entries (0,0) gather row 0 * 0 -> no-op.
__global__ __launch_bounds__(256) void prop_k(
        const float* __restrict__ zin, const float* __restrict__ x0,
        const int* __restrict__ row_off, const int2* __restrict__ ep,
        float* __restrict__ zout, int fuse_ln,
        const float* __restrict__ gamma, const float* __restrict__ beta) {
    int wave = (blockIdx.x * 256 + threadIdx.x) >> 6;
    int lane = threadIdx.x & 63;
    int half = lane >> 5;
    int l32  = lane & 31;
    int node = wave * 2 + half;
    if (node >= N_NODES) return;
    int s0 = row_off[node];
    int s1 = row_off[node + 1];                    // padded degree (x8)
    int deg = s1 - s0;
    int degO = __shfl(deg, lane ^ 32);
    int nch = (max(deg, degO) + 31) >> 5;          // wave-uniform chunk count
    const float4* z4 = (const float4*)zin;
    float4 acc = make_float4(0.f, 0.f, 0.f, 0.f);
    int hb = half << 5;
    for (int c = 0; c < nch; ++c) {
        int base = s0 + (c << 5);
        int cnt = min(max(s1 - base, 0), 32);      // per-half, multiple of 8
        int2 p = make_int2(0, 0);
        if (l32 < cnt) p = ep[base + l32];
        int cmax = max(cnt, __shfl(cnt, lane ^ 32));   // wave-uniform
        for (int j = 0; j < cmax; j += 8) {
            int sb = hb + j;
            int   o0 = __shfl(p.x, sb + 0); float w0 = __int_as_float(__shfl(p.y, sb + 0));
            int   o1 = __shfl(p.x, sb + 1); float w1 = __int_as_float(__shfl(p.y, sb + 1));
            int   o2 = __shfl(p.x, sb + 2); float w2 = __int_as_float(__shfl(p.y, sb + 2));
            int   o3 = __shfl(p.x, sb + 3); float w3 = __int_as_float(__shfl(p.y, sb + 3));
            int   o4 = __shfl(p.x, sb + 4); float w4 = __int_as_float(__shfl(p.y, sb + 4));
            int   o5 = __shfl(p.x, sb + 5); float w5 = __int_as_float(__shfl(p.y, sb + 5));
            int   o6 = __shfl(p.x, sb + 6); float w6 = __int_as_float(__shfl(p.y, sb + 6));
            int   o7 = __shfl(p.x, sb + 7); float w7 = __int_as_float(__shfl(p.y, sb + 7));
            float4 v0 = z4[o0 + l32];
            float4 v1 = z4[o1 + l32];
            float4 v2 = z4[o2 + l32];
            float4 v3 = z4[o3 + l32];
            float4 v4 = z4[o4 + l32];
            float4 v5 = z4[o5 + l32];
            float4 v6 = z4[o6 + l32];
            float4 v7 = z4[o7 + l32];
            acc.x = fmaf(w0, v0.x, acc.x); acc.y = fmaf(w0, v0.y, acc.y);
            acc.z = fmaf(w0, v0.z, acc.z); acc.w = fmaf(w0, v0.w, acc.w);
            acc.x = fmaf(w1, v1.x, acc.x); acc.y = fmaf(w1, v1.y, acc.y);
            acc.z = fmaf(w1, v1.z, acc.z); acc.w = fmaf(w1, v1.w, acc.w);
            acc.x = fmaf(w2, v2.x, acc.x); acc.y = fmaf(w2, v2.y, acc.y);
            acc.z = fmaf(w2, v2.z, acc.z); acc.w = fmaf(w2, v2.w, acc.w);
            acc.x = fmaf(w3, v3.x, acc.x); acc.y = fmaf(w3, v3.y, acc.y);
            acc.z = fmaf(w3, v3.z, acc.z); acc.w = fmaf(w3, v3.w, acc.w);
            acc.x = fmaf(w4, v4.x, acc.x); acc.y = fmaf(w4, v4.y, acc.y);
            acc.z = fmaf(w4, v4.z, acc.z); acc.w = fmaf(w4, v4.w, acc.w);
            acc.x = fmaf(w5, v5.x, acc.x); acc.y = fmaf(w5, v5.y, acc.y);
            acc.z = fmaf(w5, v5.z, acc.z); acc.w = fmaf(w5, v5.w, acc.w);
            acc.x = fmaf(w6, v6.x, acc.x); acc.y = fmaf(w6, v6.y, acc.y);
            acc.z = fmaf(w6, v6.z, acc.z); acc.w = fmaf(w6, v6.w, acc.w);
            acc.x = fmaf(w7, v7.x, acc.x); acc.y = fmaf(w7, v7.y, acc.y);
            acc.z = fmaf(w7, v7.z, acc.z); acc.w = fmaf(w7, v7.w, acc.w);
        }
    }
    float4 xv = ((const float4*)x0)[(size_t)node * 32 + l32];
    float4 z;
    z.x = fmaf(ALPHA, xv.x, acc.x);
    z.y = fmaf(ALPHA, xv.y, acc.y);
    z.z = fmaf(ALPHA, xv.z, acc.z);
    z.w = fmaf(ALPHA, xv.w, acc.w);
    float4 o;
    if (fuse_ln) {
        float4 h;
        h.x = gelu_exact(z.x); h.y = gelu_exact(z.y);
        h.z = gelu_exact(z.z); h.w = gelu_exact(z.w);
        float sum = h.x + h.y + h.z + h.w;
        for (int off = 16; off; off >>= 1) sum += __shfl_xor(sum, off); // in-half
        float mu = sum * (1.0f / 128.0f);
        float4 d;
        d.x = h.x - mu; d.y = h.y - mu; d.z = h.z - mu; d.w = h.w - mu;
        float vs = d.x * d.x + d.y * d.y + d.z * d.z + d.w * d.w;
        for (int off = 16; off; off >>= 1) vs += __shfl_xor(vs, off);
        float inv = rsqrtf(vs * (1.0f / 128.0f) + LN_EPS);
        float4 g4 = ((const float4*)gamma)[l32];
        float4 b4 = ((const float4*)beta)[l32];
        o.x = g4.x * d.x * inv + b4.x;
        o.y = g4.y * d.y * inv + b4.y;
        o.z = g4.z * d.z * inv + b4.z;
        o.w = g4.w * d.w * inv + b4.w;
    } else {
        o = z;
    }
    ((float4*)zout)[(size_t)node * 32 + l32] = o;
}

// ---------------------------------------------------------------------------
// Decoder: out = H @ Wdec^T -> [N, 64]. float4 H loads; lane = out channel.
__global__ __launch_bounds__(1024) void decoder_k(
        const float* __restrict__ H, const float* __restrict__ Wdec,
        float* __restrict__ out) {
    __shared__ float WT[HID_C * 65];           // WT[k*65 + o]: reads conflict-free
    for (int i = threadIdx.x; i < OUT_C * HID_C; i += 1024) {
        int o = i >> 7, k = i & 127;
        WT[k * 65 + o] = Wdec[i];
    }
    __syncthreads();
    int lane = threadIdx.x & 63;
    int wid  = threadIdx.x >> 6;
    int wstride = gridDim.x * 16;
    for (int grp = blockIdx.x * 16 + wid; grp * 4 < N_NODES; grp += wstride) {
        int r0 = grp * 4;
        const float4* h4 = (const float4*)(H + (size_t)r0 * HID_C);
        float a0 = 0, a1 = 0, a2 = 0, a3 = 0;
#pragma unroll 2
        for (int k4 = 0; k4 < 32; ++k4) {
            float4 h0 = h4[k4];
            float4 h1 = h4[32 + k4];
            float4 h2 = h4[64 + k4];
            float4 h3 = h4[96 + k4];
            int k = k4 * 4;
            float w0 = WT[(k + 0) * 65 + lane];
            float w1 = WT[(k + 1) * 65 + lane];
            float w2 = WT[(k + 2) * 65 + lane];
            float w3 = WT[(k + 3) * 65 + lane];
            a0 = fmaf(h0.x, w0, a0); a0 = fmaf(h0.y, w1, a0);
            a0 = fmaf(h0.z, w2, a0); a0 = fmaf(h0.w, w3, a0);
            a1 = fmaf(h1.x, w0, a1); a1 = fmaf(h1.y, w1, a1);
            a1 = fmaf(h1.z, w2, a1); a1 = fmaf(h1.w, w3, a1);
            a2 = fmaf(h2.x, w0, a2); a2 = fmaf(h2.y, w1, a2);
            a2 = fmaf(h2.z, w2, a2); a2 = fmaf(h2.w, w3, a2);
            a3 = fmaf(h3.x, w0, a3); a3 = fmaf(h3.y, w1, a3);
            a3 = fmaf(h3.z, w2, a3); a3 = fmaf(h3.w, w3, a3);
        }
        out[(size_t)r0 * OUT_C + lane]       = a0;
        out[(size_t)(r0 + 1) * OUT_C + lane] = a1;
        out[(size_t)(r0 + 2) * OUT_C + lane] = a2;
        out[(size_t)(r0 + 3) * OUT_C + lane] = a3;
    }
}

// ---------------------------------------------------------------------------
extern "C" void kernel_launch(void* const* d_in, const int* in_sizes, int n_in,
                              void* d_out, int out_size, void* d_ws, size_t ws_size,
                              hipStream_t stream) {
    const float* x     = (const float*)d_in[0];
    const int*   ei    = (const int*)d_in[1];   // [2, E] int32
    const float* ew    = (const float*)d_in[2];
    const float* Wenc  = (const float*)d_in[3];
    const float* Wdec  = (const float*)d_in[4];
    const float* gamma = (const float*)d_in[5];
    const float* beta  = (const float*)d_in[6];
    float* out = (float*)d_out;

    const int* src = ei;
    const int* dst = ei + N_EDGES;

    char* p = (char*)d_ws;
    auto carve = [&](size_t bytes) -> void* {
        void* r = (void*)p;
        p += (bytes + 255) & ~(size_t)255;
        return r;
    };
    int*  counts  = (int*)carve(SCAN_N * sizeof(int));
    int*  fillpos = (int*)carve(SCAN_N * sizeof(int));
    int*  row_off = (int*)carve(SCAN_N * sizeof(int));
    int*  bsum    = (int*)carve(SCAN_BLOCKS * sizeof(int));
    int2* ep      = (int2*)carve((size_t)EP_CAP * sizeof(int2));
    float* H  = (float*)carve((size_t)N_NODES * HID_C * sizeof(float));
    float* ZA = (float*)carve((size_t)N_NODES * HID_C * sizeof(float));
    float* ZB = (float*)carve((size_t)N_NODES * HID_C * sizeof(float));

    // CSR build (per launch; deterministic work each call)
    hipMemsetAsync(counts, 0, SCAN_N * sizeof(int), stream);
    hipMemsetAsync(ep, 0, (size_t)EP_CAP * sizeof(int2), stream);  // pads -> (0,0)
    count_k<<<(N_EDGES + 255) / 256, 256, 0, stream>>>(dst, counts);
    scan1_k<<<SCAN_BLOCKS, 1024, 0, stream>>>(counts, bsum);
    scan2_k<<<1, 128, 0, stream>>>(bsum);
    scan3_k<<<SCAN_BLOCKS, 1024, 0, stream>>>(counts, bsum, row_off, fillpos);
    bucket_k<<<(N_EDGES + 255) / 256, 256, 0, stream>>>(src, dst, ew, fillpos, ep);

    // Encoder
    encoder_k<<<512, 1024, 0, stream>>>(x, Wenc, gamma, beta, H);

    const int prop_blocks = (N_NODES + 7) / 8;   // 2 nodes/wave * 4 waves/block
    float* bufs[2] = {ZA, ZB};
    for (int l = 0; l < NLAYERS; ++l) {
        const float* zin = H;                     // x0 = H (layer input)
        for (int k = 0; k < KSTEPS; ++k) {
            int last = (k == KSTEPS - 1);
            float* zout = last ? H : bufs[k & 1]; // fused gelu+LN writes H in place
            prop_k<<<prop_blocks, 256, 0, stream>>>(zin, H, row_off, ep, zout,
                                                    last, gamma, beta);
            zin = zout;
        }
    }

    decoder_k<<<512, 1024, 0, stream>>>(H, Wdec, out);
}

// Round 5
// 2815.360 us; speedup vs baseline: 1.9360x; 1.9360x over previous
//
#include <hip/hip_runtime.h>
#include <math.h>

#define N_NODES 100000
#define N_EDGES 1600000
#define IN_C 128
#define HID_C 128
#define OUT_C 64
#define NLAYERS 4
#define KSTEPS 10
#define ALPHA 0.1f
#define LN_EPS 1e-5f

#define SCAN_N (N_NODES + 1)
#define SCAN_BLOCKS ((SCAN_N + 1023) / 1024)     // 98
#define EP_CAP 2400000                            // 1.6M edges + <=7 pad/node

__device__ __forceinline__ float gelu_exact(float x) {
    return 0.5f * x * (1.0f + erff(x * 0.70710678118654752f));
}

// Pack two fp32 into bf16x2 (round-to-nearest-even). a -> low (ch 2l), b -> high.
__device__ __forceinline__ unsigned pack_bf16_rne(float a, float b) {
    unsigned ua = __float_as_uint(a);
    unsigned ub = __float_as_uint(b);
    ua = (ua + 0x7fffu + ((ua >> 16) & 1u)) >> 16;
    ub = (ub + 0x7fffu + ((ub >> 16) & 1u)) >> 16;
    return (ub << 16) | ua;
}
__device__ __forceinline__ float bf_lo(unsigned d) { return __uint_as_float(d << 16); }
__device__ __forceinline__ float bf_hi(unsigned d) { return __uint_as_float(d & 0xffff0000u); }

// ---------------------------------------------------------------------------
// CSR build: count in-degree per dst
__global__ void count_k(const int* __restrict__ dst, int* __restrict__ counts) {
    int e = blockIdx.x * blockDim.x + threadIdx.x;
    if (e < N_EDGES) atomicAdd(&counts[dst[e]], 1);
}

// scan1: per-block sums of padded (x8) counts
__global__ __launch_bounds__(1024) void scan1_k(const int* __restrict__ counts,
                                                int* __restrict__ bsum) {
    __shared__ int s[1024];
    int i = blockIdx.x * 1024 + threadIdx.x;
    int c = 0;
    if (i < N_NODES) c = (counts[i] + 7) & ~7;
    s[threadIdx.x] = c;
    __syncthreads();
    for (int off = 512; off; off >>= 1) {
        if (threadIdx.x < off) s[threadIdx.x] += s[threadIdx.x + off];
        __syncthreads();
    }
    if (threadIdx.x == 0) bsum[blockIdx.x] = s[0];
}

// scan2: exclusive scan of the 98 block sums
__global__ void scan2_k(int* __restrict__ bsum) {
    __shared__ int s[128];
    int t = threadIdx.x;
    s[t] = (t < SCAN_BLOCKS) ? bsum[t] : 0;
    __syncthreads();
    for (int off = 1; off < 128; off <<= 1) {
        int v = (t >= off) ? s[t - off] : 0;
        __syncthreads();
        s[t] += v;
        __syncthreads();
    }
    if (t < SCAN_BLOCKS) bsum[t] = (t == 0) ? 0 : s[t - 1];
}

// scan3: per-block exclusive scan + block offset -> row_off / fill_pos
__global__ __launch_bounds__(1024) void scan3_k(const int* __restrict__ counts,
                                                const int* __restrict__ bsum,
                                                int* __restrict__ row_off,
                                                int* __restrict__ fill_pos) {
    __shared__ int s[1024];
    int i = blockIdx.x * 1024 + threadIdx.x;
    int c = 0;
    if (i < N_NODES) c = (counts[i] + 7) & ~7;
    s[threadIdx.x] = c;
    __syncthreads();
    for (int off = 1; off < 1024; off <<= 1) {
        int v = (threadIdx.x >= off) ? s[threadIdx.x - off] : 0;
        __syncthreads();
        s[threadIdx.x] += v;
        __syncthreads();
    }
    if (i <= N_NODES) {
        int excl = s[threadIdx.x] - c + bsum[blockIdx.x];
        row_off[i] = excl;
        fill_pos[i] = excl;
    }
}

// Bucket edges by dst; pack (src*64 [bf162-row offset], (1-alpha)*w).
// Pad slots stay (0,0.0f) from the ep memset -> gather row 0 * 0 -> no-op.
__global__ void bucket_k(const int* __restrict__ src, const int* __restrict__ dst,
                         const float* __restrict__ w,
                         int* __restrict__ fill_pos, int2* __restrict__ ep) {
    int e = blockIdx.x * blockDim.x + threadIdx.x;
    if (e >= N_EDGES) return;
    int d = dst[e];
    int pos = atomicAdd(&fill_pos[d], 1);
    float ws = (1.0f - ALPHA) * w[e];
    ep[pos] = make_int2(src[e] << 6, __float_as_int(ws));
}

// ---------------------------------------------------------------------------
// Encoder: H(bf16) = gelu(LN(x @ Wenc^T)).
// block=1024 (16 waves); wave: 4 rows; lane holds channel pair (2l, 2l+1).
// x rows staged into wave-private LDS via 2 coalesced float4 loads; inner-loop
// x reads are wave-uniform LDS broadcasts (free), weights ds_read_b64 2-way.
__global__ __launch_bounds__(1024) void encoder_k(
        const float* __restrict__ x, const float* __restrict__ Wenc,
        const float* __restrict__ gamma, const float* __restrict__ beta,
        unsigned* __restrict__ H) {
    __shared__ float WT[IN_C * 130];           // WT[k*130 + c]
    __shared__ float XS[16][512];              // per-wave 4-row x tile
    for (int i = threadIdx.x; i < IN_C * HID_C; i += 1024) {
        int c = i >> 7, k = i & 127;
        WT[k * 130 + c] = Wenc[i];
    }
    __syncthreads();
    int lane = threadIdx.x & 63;
    int wid  = threadIdx.x >> 6;
    const float2* WT2 = (const float2*)WT;     // index k*65 + lane
    float2 gb = ((const float2*)gamma)[lane];
    float2 bb = ((const float2*)beta)[lane];
    int wstride = gridDim.x * 16;
    float* xs = XS[wid];
    for (int grp = blockIdx.x * 16 + wid; grp * 4 < N_NODES; grp += wstride) {
        int r0 = grp * 4;
        // stage 4 rows (512 floats) with 2 coalesced lane-parallel float4 loads
        const float4* xr = (const float4*)(x + (size_t)r0 * IN_C);
        ((float4*)xs)[lane]      = xr[lane];        // rows r0, r0+1
        ((float4*)xs)[64 + lane] = xr[64 + lane];   // rows r0+2, r0+3
        __builtin_amdgcn_wave_barrier();            // wave-private: no block barrier
        float a0x = 0, a0y = 0, a1x = 0, a1y = 0;
        float a2x = 0, a2y = 0, a3x = 0, a3y = 0;
        const float4* xs4 = (const float4*)xs;
#pragma unroll 4
        for (int k4 = 0; k4 < 32; ++k4) {
            float4 xv0 = xs4[k4];
            float4 xv1 = xs4[32 + k4];
            float4 xv2 = xs4[64 + k4];
            float4 xv3 = xs4[96 + k4];
            int k = k4 * 4;
            float2 w0 = WT2[(k + 0) * 65 + lane];
            float2 w1 = WT2[(k + 1) * 65 + lane];
            float2 w2 = WT2[(k + 2) * 65 + lane];
            float2 w3 = WT2[(k + 3) * 65 + lane];
#define ENC_ROW(ax, ay, xv)                                      \
            ax = fmaf(xv.x, w0.x, ax); ay = fmaf(xv.x, w0.y, ay); \
            ax = fmaf(xv.y, w1.x, ax); ay = fmaf(xv.y, w1.y, ay); \
            ax = fmaf(xv.z, w2.x, ax); ay = fmaf(xv.z, w2.y, ay); \
            ax = fmaf(xv.w, w3.x, ax); ay = fmaf(xv.w, w3.y, ay);
            ENC_ROW(a0x, a0y, xv0)
            ENC_ROW(a1x, a1y, xv1)
            ENC_ROW(a2x, a2y, xv2)
            ENC_ROW(a3x, a3y, xv3)
#undef ENC_ROW
        }
        __builtin_amdgcn_wave_barrier();
#define ENC_EPI(ax, ay, row)                                               \
        {                                                                   \
            float sum = ax + ay;                                            \
            for (int off = 32; off; off >>= 1) sum += __shfl_xor(sum, off); \
            float mu = sum * (1.0f / 128.0f);                               \
            float d0 = ax - mu, d1 = ay - mu;                               \
            float vs = d0 * d0 + d1 * d1;                                   \
            for (int off = 32; off; off >>= 1) vs += __shfl_xor(vs, off);   \
            float inv = rsqrtf(vs * (1.0f / 128.0f) + LN_EPS);              \
            float o0 = gelu_exact(gb.x * d0 * inv + bb.x);                  \
            float o1 = gelu_exact(gb.y * d1 * inv + bb.y);                  \
            H[(size_t)(row)*64 + lane] = pack_bf16_rne(o0, o1);             \
        }
        ENC_EPI(a0x, a0y, r0)
        ENC_EPI(a1x, a1y, r0 + 1)
        ENC_EPI(a2x, a2y, r0 + 2)
        ENC_EPI(a3x, a3y, r0 + 3)
#undef ENC_EPI
    }
}

// ---------------------------------------------------------------------------
// One APPNP step (pull), bf16 features. Wave per node; lane holds channel pair
// (2l, 2l+1) as one bf16x2 dword -> 256 B/row gathers, 8 in flight.
// Accumulate fp32; store bf16 (RNE). fuse_ln: gelu+LN on the last K-step.
__global__ __launch_bounds__(256) void prop_k(
        const unsigned* __restrict__ zin, const unsigned* __restrict__ x0,
        const int* __restrict__ row_off, const int2* __restrict__ ep,
        unsigned* __restrict__ zout, int fuse_ln,
        const float* __restrict__ gamma, const float* __restrict__ beta) {
    int gw = (blockIdx.x * 256 + threadIdx.x) >> 6;   // node id
    if (gw >= N_NODES) return;
    int lane = threadIdx.x & 63;
    int s0 = row_off[gw];
    int s1 = row_off[gw + 1];                          // padded degree (x8)
    float sx = 0.f, sy = 0.f;
    for (int base = s0; base < s1; base += 64) {
        int cnt = min(64, s1 - base);                  // multiple of 8
        int2 p = make_int2(0, 0);
        if (lane < cnt) p = ep[base + lane];
        for (int j = 0; j < cnt; j += 8) {
            int   o0 = __shfl(p.x, j + 0); float w0 = __int_as_float(__shfl(p.y, j + 0));
            int   o1 = __shfl(p.x, j + 1); float w1 = __int_as_float(__shfl(p.y, j + 1));
            int   o2 = __shfl(p.x, j + 2); float w2 = __int_as_float(__shfl(p.y, j + 2));
            int   o3 = __shfl(p.x, j + 3); float w3 = __int_as_float(__shfl(p.y, j + 3));
            int   o4 = __shfl(p.x, j + 4); float w4 = __int_as_float(__shfl(p.y, j + 4));
            int   o5 = __shfl(p.x, j + 5); float w5 = __int_as_float(__shfl(p.y, j + 5));
            int   o6 = __shfl(p.x, j + 6); float w6 = __int_as_float(__shfl(p.y, j + 6));
            int   o7 = __shfl(p.x, j + 7); float w7 = __int_as_float(__shfl(p.y, j + 7));
            unsigned d0 = zin[o0 + lane];
            unsigned d1 = zin[o1 + lane];
            unsigned d2 = zin[o2 + lane];
            unsigned d3 = zin[o3 + lane];
            unsigned d4 = zin[o4 + lane];
            unsigned d5 = zin[o5 + lane];
            unsigned d6 = zin[o6 + lane];
            unsigned d7 = zin[o7 + lane];
            sx = fmaf(w0, bf_lo(d0), sx); sy = fmaf(w0, bf_hi(d0), sy);
            sx = fmaf(w1, bf_lo(d1), sx); sy = fmaf(w1, bf_hi(d1), sy);
            sx = fmaf(w2, bf_lo(d2), sx); sy = fmaf(w2, bf_hi(d2), sy);
            sx = fmaf(w3, bf_lo(d3), sx); sy = fmaf(w3, bf_hi(d3), sy);
            sx = fmaf(w4, bf_lo(d4), sx); sy = fmaf(w4, bf_hi(d4), sy);
            sx = fmaf(w5, bf_lo(d5), sx); sy = fmaf(w5, bf_hi(d5), sy);
            sx = fmaf(w6, bf_lo(d6), sx); sy = fmaf(w6, bf_hi(d6), sy);
            sx = fmaf(w7, bf_lo(d7), sx); sy = fmaf(w7, bf_hi(d7), sy);
        }
    }
    unsigned xd = x0[(size_t)gw * 64 + lane];
    float zx = fmaf(ALPHA, bf_lo(xd), sx);
    float zy = fmaf(ALPHA, bf_hi(xd), sy);
    unsigned od;
    if (fuse_ln) {
        float h0 = gelu_exact(zx);
        float h1 = gelu_exact(zy);
        float sum = h0 + h1;
        for (int off = 32; off; off >>= 1) sum += __shfl_xor(sum, off);
        float mu = sum * (1.0f / 128.0f);
        float d0 = h0 - mu, d1 = h1 - mu;
        float vs = d0 * d0 + d1 * d1;
        for (int off = 32; off; off >>= 1) vs += __shfl_xor(vs, off);
        float inv = rsqrtf(vs * (1.0f / 128.0f) + LN_EPS);
        float2 gb = ((const float2*)gamma)[lane];
        float2 bb = ((const float2*)beta)[lane];
        od = pack_bf16_rne(gb.x * d0 * inv + bb.x, gb.y * d1 * inv + bb.y);
    } else {
        od = pack_bf16_rne(zx, zy);
    }
    zout[(size_t)gw * 64 + lane] = od;
}

// ---------------------------------------------------------------------------
// Decoder: out(fp32) = H(bf16) @ Wdec^T -> [N, 64].
// Wave: 4 rows staged to wave-private LDS via coalesced loads; lane = out ch.
__global__ __launch_bounds__(1024) void decoder_k(
        const unsigned* __restrict__ H, const float* __restrict__ Wdec,
        float* __restrict__ out) {
    __shared__ float WT[HID_C * 65];           // WT[k*65 + o]
    __shared__ unsigned XS[16][256];
    for (int i = threadIdx.x; i < OUT_C * HID_C; i += 1024) {
        int o = i >> 7, k = i & 127;
        WT[k * 65 + o] = Wdec[i];
    }
    __syncthreads();
    int lane = threadIdx.x & 63;
    int wid  = threadIdx.x >> 6;
    int wstride = gridDim.x * 16;
    unsigned* xs = XS[wid];
    for (int grp = blockIdx.x * 16 + wid; grp * 4 < N_NODES; grp += wstride) {
        int r0 = grp * 4;
        const unsigned* hp = H + (size_t)r0 * 64;
        xs[lane]       = hp[lane];
        xs[64 + lane]  = hp[64 + lane];
        xs[128 + lane] = hp[128 + lane];
        xs[192 + lane] = hp[192 + lane];
        __builtin_amdgcn_wave_barrier();
        float a0 = 0, a1 = 0, a2 = 0, a3 = 0;
#pragma unroll 4
        for (int k2 = 0; k2 < 64; ++k2) {      // channel-pair index
            float w0 = WT[(2 * k2) * 65 + lane];
            float w1 = WT[(2 * k2 + 1) * 65 + lane];
            unsigned u0 = xs[k2];
            unsigned u1 = xs[64 + k2];
            unsigned u2 = xs[128 + k2];
            unsigned u3 = xs[192 + k2];
            a0 = fmaf(bf_lo(u0), w0, a0); a0 = fmaf(bf_hi(u0), w1, a0);
            a1 = fmaf(bf_lo(u1), w0, a1); a1 = fmaf(bf_hi(u1), w1, a1);
            a2 = fmaf(bf_lo(u2), w0, a2); a2 = fmaf(bf_hi(u2), w1, a2);
            a3 = fmaf(bf_lo(u3), w0, a3); a3 = fmaf(bf_hi(u3), w1, a3);
        }
        __builtin_amdgcn_wave_barrier();
        out[(size_t)r0 * OUT_C + lane]       = a0;
        out[(size_t)(r0 + 1) * OUT_C + lane] = a1;
        out[(size_t)(r0 + 2) * OUT_C + lane] = a2;
        out[(size_t)(r0 + 3) * OUT_C + lane] = a3;
    }
}

// ---------------------------------------------------------------------------
extern "C" void kernel_launch(void* const* d_in, const int* in_sizes, int n_in,
                              void* d_out, int out_size, void* d_ws, size_t ws_size,
                              hipStream_t stream) {
    const float* x     = (const float*)d_in[0];
    const int*   ei    = (const int*)d_in[1];   // [2, E] int32
    const float* ew    = (const float*)d_in[2];
    const float* Wenc  = (const float*)d_in[3];
    const float* Wdec  = (const float*)d_in[4];
    const float* gamma = (const float*)d_in[5];
    const float* beta  = (const float*)d_in[6];
    float* out = (float*)d_out;

    const int* src = ei;
    const int* dst = ei + N_EDGES;

    char* p = (char*)d_ws;
    auto carve = [&](size_t bytes) -> void* {
        void* r = (void*)p;
        p += (bytes + 255) & ~(size_t)255;
        return r;
    };
    int*  counts  = (int*)carve(SCAN_N * sizeof(int));
    int*  fillpos = (int*)carve(SCAN_N * sizeof(int));
    int*  row_off = (int*)carve(SCAN_N * sizeof(int));
    int*  bsum    = (int*)carve(SCAN_BLOCKS * sizeof(int));
    int2* ep      = (int2*)carve((size_t)EP_CAP * sizeof(int2));
    unsigned* H  = (unsigned*)carve((size_t)N_NODES * 64 * sizeof(unsigned));
    unsigned* ZA = (unsigned*)carve((size_t)N_NODES * 64 * sizeof(unsigned));
    unsigned* ZB = (unsigned*)carve((size_t)N_NODES * 64 * sizeof(unsigned));

    // CSR build (per launch; deterministic work each call)
    hipMemsetAsync(counts, 0, SCAN_N * sizeof(int), stream);
    hipMemsetAsync(ep, 0, (size_t)EP_CAP * sizeof(int2), stream);  // pads -> (0,0)
    count_k<<<(N_EDGES + 255) / 256, 256, 0, stream>>>(dst, counts);
    scan1_k<<<SCAN_BLOCKS, 1024, 0, stream>>>(counts, bsum);
    scan2_k<<<1, 128, 0, stream>>>(bsum);
    scan3_k<<<SCAN_BLOCKS, 1024, 0, stream>>>(counts, bsum, row_off, fillpos);
    bucket_k<<<(N_EDGES + 255) / 256, 256, 0, stream>>>(src, dst, ew, fillpos, ep);

    // Encoder
    encoder_k<<<512, 1024, 0, stream>>>(x, Wenc, gamma, beta, H);

    const int prop_blocks = (N_NODES + 3) / 4;   // 1 node/wave, 4 waves/block
    unsigned* bufs[2] = {ZA, ZB};
    for (int l = 0; l < NLAYERS; ++l) {
        const unsigned* zin = H;                  // x0 = H (layer input)
        for (int k = 0; k < KSTEPS; ++k) {
            int last = (k == KSTEPS - 1);
            unsigned* zout = last ? H : bufs[k & 1];
            prop_k<<<prop_blocks, 256, 0, stream>>>(zin, H, row_off, ep, zout,
                                                    last, gamma, beta);
            zin = zout;
        }
    }

    decoder_k<<<512, 1024, 0, stream>>>(H, Wdec, out);
}